// Round 9
// baseline (382.092 us; speedup 1.0000x reference)
//
#include <hip/hip_runtime.h>

#define NN 50000
#define NE 800000
#define F 128
#define NBLK ((NN + 255) / 256)   // 196 scan blocks
#define NMT (NN / 16)             // 3125 m-tiles, exact
#define C2CGRID 512               // 2 blocks/CU, grid-stride over m-tiles
#define NQ (NE / 4)               // 200000 edge-quads
#define EBLK 4096                 // k_edge grid
#define QPB ((NQ + EBLK - 1) / EBLK)  // 49 quad-slots per block
#define CVB ((NE + 255) / 256)    // 3125 convert blocks (fused into k_prep)

typedef __attribute__((ext_vector_type(4))) unsigned short ushort4_t;
typedef __attribute__((ext_vector_type(8))) unsigned short ushort8_t;
typedef __attribute__((ext_vector_type(8))) short bf16x8;
typedef __attribute__((ext_vector_type(4))) float f32x4;

#define MFMA16x16x32 __builtin_amdgcn_mfma_f32_16x16x32_bf16

__device__ __forceinline__ float b2f(unsigned short u) {
    return __uint_as_float((unsigned int)u << 16);
}
__device__ __forceinline__ unsigned short f2b(float f) {
    unsigned int u = __float_as_uint(f);
    return (unsigned short)((u + 0x7fffu + ((u >> 16) & 1u)) >> 16);
}

// ---------------------------------------------------------------------------
// dtype probe (block 0) + cnt[] zeroing (blocks 1..196).
// ---------------------------------------------------------------------------
__global__ void k_detect(const unsigned int* __restrict__ w, int* __restrict__ nz,
                         int* __restrict__ cnt) {
    if (blockIdx.x == 0) {
        __shared__ int s;
        if (threadIdx.x == 0) s = 0;
        __syncthreads();
        if (w[2 * threadIdx.x + 1] != 0u) atomicAdd(&s, 1);
        __syncthreads();
        if (threadIdx.x == 0) *nz = s;
    } else {
        int i = (blockIdx.x - 1) * 256 + threadIdx.x;
        if (i < NN) cnt[i] = 0;
    }
}

// ---------------------------------------------------------------------------
// Fused prep + edge-convert. The 800K returning atomics (~40us) are the
// structural floor for the histogram+seq; merging at least overlaps the
// bf16 casts and weight preps under them.
// ---------------------------------------------------------------------------
__device__ __forceinline__ void prepw_conv_body(int i, const float* __restrict__ WA,
                                                const float* __restrict__ WB,
                                                unsigned short* __restrict__ hi,
                                                unsigned short* __restrict__ lo) {
    int n = i >> 8, k = i & 255;
    float v = (k < 128) ? WA[(size_t)k * F + n] : WB[(size_t)(k - 128) * F + n];
    unsigned short h = f2b(v);
    hi[(size_t)n * 256 + k] = h;
    lo[(size_t)n * 256 + k] = f2b(v - b2f(h));
}

__global__ void k_prep(const float* __restrict__ x, unsigned short* __restrict__ xh,
                       const float* __restrict__ W1l, const float* __restrict__ W1r,
                       unsigned short* __restrict__ w1hi, unsigned short* __restrict__ w1lo,
                       const float* __restrict__ W2l, const float* __restrict__ W2r,
                       unsigned short* __restrict__ w2hi, unsigned short* __restrict__ w2lo,
                       const float* __restrict__ Wc1,
                       unsigned short* __restrict__ wchi, unsigned short* __restrict__ wclo,
                       const void* __restrict__ ei, const int* __restrict__ nz,
                       unsigned int* __restrict__ sd, int* __restrict__ seq,
                       int* __restrict__ cnt) {
    int b = blockIdx.x;
    if (b < 6250) {                       // cast: NN*F/4 = 1.6M float4 groups
        int i = b * 256 + threadIdx.x;
        float4 v = ((const float4*)x)[i];
        ushort4_t o;
        o.x = f2b(v.x); o.y = f2b(v.y); o.z = f2b(v.z); o.w = f2b(v.w);
        ((ushort4_t*)xh)[i] = o;
    } else if (b < 6378) {
        prepw_conv_body((b - 6250) * 256 + threadIdx.x, W1l, W1r, w1hi, w1lo);
    } else if (b < 6506) {
        prepw_conv_body((b - 6378) * 256 + threadIdx.x, W2l, W2r, w2hi, w2lo);
    } else if (b < 6634) {
        int i = (b - 6506) * 256 + threadIdx.x;
        int n = i >> 7, k = i & 127;
        float v = (n < 128) ? Wc1[(size_t)k * F + n]
                            : Wc1[(size_t)(128 + k) * F + (n - 128)];
        unsigned short h = f2b(v);
        wchi[(size_t)n * 128 + k] = h;
        wclo[(size_t)n * 128 + k] = f2b(v - b2f(h));
    } else {                              // edge-index normalize + histogram
        int e = (b - 6634) * 256 + threadIdx.x;
        if (e >= NE) return;
        int s, d;
        if (*nz == 0) {
            const long long* p = (const long long*)ei;
            s = (int)p[e];
            d = (int)p[NE + e];
        } else {
            const int* p = (const int*)ei;
            s = p[e];
            d = p[NE + e];
        }
        sd[e] = (unsigned)s | ((unsigned)d << 16);
        seq[e] = atomicAdd(&cnt[d], 1);
    }
}

// ---- exclusive scan of cnt[NN] -> rowptr[NN+1]
__global__ void k_bsum(const int* __restrict__ cnt, int* __restrict__ bsum) {
    __shared__ int s[256];
    int i = blockIdx.x * 256 + threadIdx.x;
    s[threadIdx.x] = (i < NN) ? cnt[i] : 0;
    __syncthreads();
    for (int st = 128; st > 0; st >>= 1) {
        if (threadIdx.x < st) s[threadIdx.x] += s[threadIdx.x + st];
        __syncthreads();
    }
    if (threadIdx.x == 0) bsum[blockIdx.x] = s[0];
}

__global__ void k_bscan(const int* __restrict__ bsum, int* __restrict__ boff) {
    __shared__ int s[256];
    int v = (threadIdx.x < NBLK) ? bsum[threadIdx.x] : 0;
    s[threadIdx.x] = v;
    __syncthreads();
    for (int st = 1; st < 256; st <<= 1) {
        int t = (threadIdx.x >= st) ? s[threadIdx.x - st] : 0;
        __syncthreads();
        s[threadIdx.x] += t;
        __syncthreads();
    }
    if (threadIdx.x < NBLK) boff[threadIdx.x] = s[threadIdx.x] - v;
}

__global__ void k_scan2(const int* __restrict__ cnt, const int* __restrict__ boff,
                        int* __restrict__ rowptr) {
    __shared__ int s[256];
    int i = blockIdx.x * 256 + threadIdx.x;
    int v = (i < NN) ? cnt[i] : 0;
    s[threadIdx.x] = v;
    __syncthreads();
    for (int st = 1; st < 256; st <<= 1) {
        int t = (threadIdx.x >= st) ? s[threadIdx.x - st] : 0;
        __syncthreads();
        s[threadIdx.x] += t;
        __syncthreads();
    }
    int excl = s[threadIdx.x] - v + boff[blockIdx.x];
    if (i < NN) rowptr[i] = excl;
    if (i == NN - 1) rowptr[NN] = excl + v;
}

// counting-sort edges by dst into ONE packed 16B record per edge:
//   rec[pos] = { src | dst<<16, ea0, ea1, ea2 }
// pos = rowptr[dst] + seq[e]  -- NO atomics (seq captured during k_prep).
__global__ void k_perm(const unsigned int* __restrict__ sd,
                       const int* __restrict__ seq,
                       const float* __restrict__ ea,
                       const int* __restrict__ rowptr,
                       int4* __restrict__ rec, int* __restrict__ rank) {
    int e = blockIdx.x * 256 + threadIdx.x;
    if (e >= NE) return;
    unsigned v = sd[e];
    int d = (int)(v >> 16);
    int pos = rowptr[d] + seq[e];
    int4 r;
    r.x = (int)v;
    r.y = __float_as_int(ea[(size_t)e * 3 + 0]);
    r.z = __float_as_int(ea[(size_t)e * 3 + 1]);
    r.w = __float_as_int(ea[(size_t)e * 3 + 2]);
    rec[pos] = r;
    rank[e] = pos;
}

// gather-reduce + mean over bf16 rows -> bf16 out. 16 lanes/node, 8 ch/lane.
__launch_bounds__(256)
__global__ void k_gather(const unsigned short* __restrict__ xin,
                         const int* __restrict__ rowptr,
                         const int4* __restrict__ rec,
                         unsigned short* __restrict__ agg) {
    int n = blockIdx.x * 16 + (threadIdx.x >> 4);
    if (n >= NN) return;
    int c = (threadIdx.x & 15) << 3;
    int beg = rowptr[n], end = rowptr[n + 1];
    float acc[8] = {};
    int j = beg;
    for (; j + 4 <= end; j += 4) {
        int s0 = rec[j].x & 0xffff;
        int s1 = rec[j + 1].x & 0xffff;
        int s2 = rec[j + 2].x & 0xffff;
        int s3 = rec[j + 3].x & 0xffff;
        ushort8_t v0 = *(const ushort8_t*)(xin + (size_t)s0 * F + c);
        ushort8_t v1 = *(const ushort8_t*)(xin + (size_t)s1 * F + c);
        ushort8_t v2 = *(const ushort8_t*)(xin + (size_t)s2 * F + c);
        ushort8_t v3 = *(const ushort8_t*)(xin + (size_t)s3 * F + c);
#pragma unroll
        for (int k = 0; k < 8; ++k)
            acc[k] += (b2f(v0[k]) + b2f(v1[k])) + (b2f(v2[k]) + b2f(v3[k]));
    }
    for (; j < end; ++j) {
        int s = rec[j].x & 0xffff;
        ushort8_t v = *(const ushort8_t*)(xin + (size_t)s * F + c);
#pragma unroll
        for (int k = 0; k < 8; ++k) acc[k] += b2f(v[k]);
    }
    float sc = 1.0f / (float)max(end - beg, 1);
    ushort8_t o;
#pragma unroll
    for (int k = 0; k < 8; ++k) o[k] = f2b(acc[k] * sc);
    *(ushort8_t*)(agg + (size_t)n * F + c) = o;
}

// ---------------------------------------------------------------------------
// Conv1 GEMM, W-in-registers (bf16 data, W exact as hi+lo, dual acc chains).
// ---------------------------------------------------------------------------
__launch_bounds__(256)
__global__ void k_mm_conv(const unsigned short* __restrict__ A1,
                          const unsigned short* __restrict__ A2,
                          const unsigned short* __restrict__ Whi,
                          const unsigned short* __restrict__ Wlo,
                          const float* __restrict__ bias,
                          unsigned short* __restrict__ Ch,
                          int relu, int nstripes) {
    int lane = threadIdx.x & 63;
    int wid = (blockIdx.x * 256 + threadIdx.x) >> 6;
    int ntile = wid & 7;
    int stripe = wid >> 3;
    int lm = lane & 15, quad = lane >> 4;

    const unsigned short* whp = Whi + (size_t)(ntile * 16 + lm) * 256 + quad * 8;
    const unsigned short* wlp = Wlo + (size_t)(ntile * 16 + lm) * 256 + quad * 8;
    bf16x8 wh[8], wl[8];
#pragma unroll
    for (int kc = 0; kc < 8; ++kc) {
        wh[kc] = *(const bf16x8*)(whp + kc * 32);
        wl[kc] = *(const bf16x8*)(wlp + kc * 32);
    }
    int nc = ntile * 16 + quad * 4;
    f32x4 bfrag = *(const f32x4*)(bias + nc);

    for (int mt = stripe; mt < NMT; mt += nstripes) {
        int m = mt * 16 + lm;
        const unsigned short* a1p = A1 + (size_t)m * F + quad * 8;
        const unsigned short* a2p = A2 + (size_t)m * F + quad * 8;
        f32x4 accH = {0.f, 0.f, 0.f, 0.f};
        f32x4 accL = {0.f, 0.f, 0.f, 0.f};
#pragma unroll
        for (int kc = 0; kc < 4; ++kc) {
            bf16x8 d = *(const bf16x8*)(a1p + kc * 32);
            accH = MFMA16x16x32(wh[kc], d, accH, 0, 0, 0);
            accL = MFMA16x16x32(wl[kc], d, accL, 0, 0, 0);
        }
#pragma unroll
        for (int kc = 0; kc < 4; ++kc) {
            bf16x8 d = *(const bf16x8*)(a2p + kc * 32);
            accH = MFMA16x16x32(wh[4 + kc], d, accH, 0, 0, 0);
            accL = MFMA16x16x32(wl[4 + kc], d, accL, 0, 0, 0);
        }
        ushort4_t u;
#pragma unroll
        for (int r = 0; r < 4; ++r) {
            float o = accH[r] + accL[r] + bfrag[r];
            if (relu) o = fmaxf(o, 0.f);
            u[r] = f2b(o);
        }
        *(ushort4_t*)(Ch + (size_t)m * F + nc) = u;
    }
}

// ---------------------------------------------------------------------------
// Fused conv2 + classifier GEMM, v5: STREAMED WEIGHTS + occupancy cap.
// Diagnosis (r4-r8): holding 48 weight frags/wave (~192 regs) pinned the
// kernel at ~2 waves/SIMD, 1 block/CU -> 49us at 9% MfmaUtil regardless of
// schedule. Fix: hold NO weights; stream all fragments from L2 (0.5MB, hot;
// ~10MB total reload traffic) and force <=128 VGPRs via launch_bounds(512,4)
// -> 2 blocks/CU, 4 waves/SIMD. Supertile=1 to cap A-frag pressure.
// Spill check: WRITE_SIZE must stay 25.0MB.
// ---------------------------------------------------------------------------
__launch_bounds__(512, 4)
__global__ void k_c2c(const unsigned short* __restrict__ A1,   // agg2
                      const unsigned short* __restrict__ A2,   // h1
                      const unsigned short* __restrict__ W2hi,
                      const unsigned short* __restrict__ W2lo,
                      const float* __restrict__ b2l,
                      const unsigned short* __restrict__ Wchi,
                      const unsigned short* __restrict__ Wclo,
                      const float* __restrict__ bc1,
                      unsigned short* __restrict__ Gs,
                      unsigned short* __restrict__ Gdb) {
    __shared__ unsigned short h2s[16][136];
    int lane = threadIdx.x & 63;
    int wv = threadIdx.x >> 6;            // 0..7
    int lm = lane & 15, quad = lane >> 4;
    int nc = wv * 16 + quad * 4;

    // invariant weight base addresses only (weights streamed per iteration)
    const unsigned short* whp  = W2hi + (size_t)(wv * 16 + lm) * 256 + quad * 8;
    const unsigned short* wlp  = W2lo + (size_t)(wv * 16 + lm) * 256 + quad * 8;
    const unsigned short* c0hp = Wchi + (size_t)(wv * 16 + lm) * 128 + quad * 8;
    const unsigned short* c0lp = Wclo + (size_t)(wv * 16 + lm) * 128 + quad * 8;
    const unsigned short* c1hp = Wchi + (size_t)((wv + 8) * 16 + lm) * 128 + quad * 8;
    const unsigned short* c1lp = Wclo + (size_t)((wv + 8) * 16 + lm) * 128 + quad * 8;
    f32x4 bfrag2 = *(const f32x4*)(b2l + nc);
    f32x4 bfragc = *(const f32x4*)(bc1 + nc);

    for (int mt = blockIdx.x; mt < NMT; mt += C2CGRID) {
        int m = mt * 16 + lm;
        // ---- phase A: conv2 n-slice wv, weights streamed
        const unsigned short* a1p = A1 + (size_t)m * F + quad * 8;
        const unsigned short* a2p = A2 + (size_t)m * F + quad * 8;
        f32x4 accH = {0.f, 0.f, 0.f, 0.f};
        f32x4 accL = {0.f, 0.f, 0.f, 0.f};
#pragma unroll
        for (int kc = 0; kc < 4; ++kc) {
            bf16x8 d = *(const bf16x8*)(a1p + kc * 32);
            bf16x8 wh = *(const bf16x8*)(whp + kc * 32);
            bf16x8 wl = *(const bf16x8*)(wlp + kc * 32);
            accH = MFMA16x16x32(wh, d, accH, 0, 0, 0);
            accL = MFMA16x16x32(wl, d, accL, 0, 0, 0);
        }
#pragma unroll
        for (int kc = 0; kc < 4; ++kc) {
            bf16x8 d = *(const bf16x8*)(a2p + kc * 32);
            bf16x8 wh = *(const bf16x8*)(whp + (4 + kc) * 32);
            bf16x8 wl = *(const bf16x8*)(wlp + (4 + kc) * 32);
            accH = MFMA16x16x32(wh, d, accH, 0, 0, 0);
            accL = MFMA16x16x32(wl, d, accL, 0, 0, 0);
        }
        ushort4_t u;
#pragma unroll
        for (int r = 0; r < 4; ++r)
            u[r] = f2b(accH[r] + accL[r] + bfrag2[r]);
        *(ushort4_t*)(&h2s[lm][nc]) = u;
        __syncthreads();

        // ---- phase B: cls from LDS h2 tile, weights streamed
        const unsigned short* ap = &h2s[lm][quad * 8];
        f32x4 g0H = {0.f,0.f,0.f,0.f}, g0L = {0.f,0.f,0.f,0.f};
        f32x4 g1H = {0.f,0.f,0.f,0.f}, g1L = {0.f,0.f,0.f,0.f};
#pragma unroll
        for (int kc = 0; kc < 4; ++kc) {
            bf16x8 d = *(const bf16x8*)(ap + kc * 32);
            bf16x8 h0 = *(const bf16x8*)(c0hp + kc * 32);
            bf16x8 l0 = *(const bf16x8*)(c0lp + kc * 32);
            bf16x8 h1 = *(const bf16x8*)(c1hp + kc * 32);
            bf16x8 l1 = *(const bf16x8*)(c1lp + kc * 32);
            g0H = MFMA16x16x32(h0, d, g0H, 0, 0, 0);
            g0L = MFMA16x16x32(l0, d, g0L, 0, 0, 0);
            g1H = MFMA16x16x32(h1, d, g1H, 0, 0, 0);
            g1L = MFMA16x16x32(l1, d, g1L, 0, 0, 0);
        }
        ushort4_t o0, o1;
#pragma unroll
        for (int r = 0; r < 4; ++r) {
            o0[r] = f2b(g0H[r] + g0L[r]);
            o1[r] = f2b(g1H[r] + g1L[r] + bfragc[r]);
        }
        *(ushort4_t*)(Gs  + (size_t)m * F + nc) = o0;
        *(ushort4_t*)(Gdb + (size_t)m * F + nc) = o1;
        __syncthreads();
    }
}

// ---------------------------------------------------------------------------
// edge classifier over dst-sorted packed records, 4 edges per 16-lane group:
// 8 G-row loads in flight per group, bc1 pre-folded into Gdb. XCD-contiguous
// chunking keeps each XCD's dst window L2-resident. Coalesced float4 store.
// ---------------------------------------------------------------------------
__launch_bounds__(256)
__global__ void k_edge(const unsigned short* __restrict__ Gs,
                       const unsigned short* __restrict__ Gdb,
                       const int4* __restrict__ rec,
                       const float* __restrict__ Wc1e,
                       const float* __restrict__ Wc2,
                       const float* __restrict__ bc2,
                       float* __restrict__ outsort) {
    int lane = threadIdx.x & 15;
    int c = lane << 3;
    float w0[8], w1[8], w2[8], wc[8];
#pragma unroll
    for (int k = 0; k < 8; ++k) {
        w0[k] = Wc1e[0 * F + c + k];
        w1[k] = Wc1e[1 * F + c + k];
        w2[k] = Wc1e[2 * F + c + k];
        wc[k] = Wc2[c + k];
    }
    float bout = bc2[0];

    int subgrp = threadIdx.x >> 4;                       // 16 groups/block
    int wblk = ((blockIdx.x & 7) << 9) | (blockIdx.x >> 3);  // XCD-contiguous
    int base = wblk * QPB;
    int lim = base + QPB;
    if (lim > NQ) lim = NQ;

    for (int q = base + subgrp; q < lim; q += 16) {
        int pos = q * 4;
        int4 r0 = rec[pos];
        int4 r1 = rec[pos + 1];
        int4 r2 = rec[pos + 2];
        int4 r3 = rec[pos + 3];
        unsigned u0 = (unsigned)r0.x, u1 = (unsigned)r1.x;
        unsigned u2 = (unsigned)r2.x, u3 = (unsigned)r3.x;
        ushort8_t gs0 = *(const ushort8_t*)(Gs  + (size_t)(u0 & 0xffffu) * F + c);
        ushort8_t gd0 = *(const ushort8_t*)(Gdb + (size_t)(u0 >> 16) * F + c);
        ushort8_t gs1 = *(const ushort8_t*)(Gs  + (size_t)(u1 & 0xffffu) * F + c);
        ushort8_t gd1 = *(const ushort8_t*)(Gdb + (size_t)(u1 >> 16) * F + c);
        ushort8_t gs2 = *(const ushort8_t*)(Gs  + (size_t)(u2 & 0xffffu) * F + c);
        ushort8_t gd2 = *(const ushort8_t*)(Gdb + (size_t)(u2 >> 16) * F + c);
        ushort8_t gs3 = *(const ushort8_t*)(Gs  + (size_t)(u3 & 0xffffu) * F + c);
        ushort8_t gd3 = *(const ushort8_t*)(Gdb + (size_t)(u3 >> 16) * F + c);

        float ex0 = __int_as_float(r0.y), ey0 = __int_as_float(r0.z), ez0 = __int_as_float(r0.w);
        float ex1 = __int_as_float(r1.y), ey1 = __int_as_float(r1.z), ez1 = __int_as_float(r1.w);
        float ex2 = __int_as_float(r2.y), ey2 = __int_as_float(r2.z), ez2 = __int_as_float(r2.w);
        float ex3 = __int_as_float(r3.y), ey3 = __int_as_float(r3.z), ez3 = __int_as_float(r3.w);

        float p0 = 0.f, p1 = 0.f, p2 = 0.f, p3 = 0.f;
#pragma unroll
        for (int k = 0; k < 8; ++k) {
            float h0 = b2f(gs0[k]) + b2f(gd0[k]) + ex0 * w0[k] + ey0 * w1[k] + ez0 * w2[k];
            float h1 = b2f(gs1[k]) + b2f(gd1[k]) + ex1 * w0[k] + ey1 * w1[k] + ez1 * w2[k];
            float h2 = b2f(gs2[k]) + b2f(gd2[k]) + ex2 * w0[k] + ey2 * w1[k] + ez2 * w2[k];
            float h3 = b2f(gs3[k]) + b2f(gd3[k]) + ex3 * w0[k] + ey3 * w1[k] + ez3 * w2[k];
            p0 += fmaxf(h0, 0.f) * wc[k];
            p1 += fmaxf(h1, 0.f) * wc[k];
            p2 += fmaxf(h2, 0.f) * wc[k];
            p3 += fmaxf(h3, 0.f) * wc[k];
        }
#pragma unroll
        for (int off = 8; off > 0; off >>= 1) {
            p0 += __shfl_down(p0, off, 16);
            p1 += __shfl_down(p1, off, 16);
            p2 += __shfl_down(p2, off, 16);
            p3 += __shfl_down(p3, off, 16);
        }
        if (lane == 0) {
            float4 o;
            o.x = p0 + bout; o.y = p1 + bout; o.z = p2 + bout; o.w = p3 + bout;
            *(float4*)(outsort + pos) = o;
        }
    }
}

// out[e] = outsort[rank[e]] — coalesced read of rank + write of out;
// random reads hit the 3.2MB L2-hot outsort.
__global__ void k_unperm(const float* __restrict__ outsort,
                         const int* __restrict__ rank,
                         float* __restrict__ out) {
    int e = blockIdx.x * 256 + threadIdx.x;
    if (e >= NE) return;
    out[e] = outsort[rank[e]];
}

// ---------------------------------------------------------------------------
extern "C" void kernel_launch(void* const* d_in, const int* in_sizes, int n_in,
                              void* d_out, int out_size, void* d_ws, size_t ws_size,
                              hipStream_t stream) {
    const float* x    = (const float*)d_in[0];
    const void*  ei   = d_in[1];
    const float* ea   = (const float*)d_in[2];
    const float* W1l  = (const float*)d_in[3];
    const float* b1l  = (const float*)d_in[4];
    const float* W1r  = (const float*)d_in[5];
    const float* W2l  = (const float*)d_in[6];
    const float* b2l  = (const float*)d_in[7];
    const float* W2r  = (const float*)d_in[8];
    const float* Wc1  = (const float*)d_in[9];
    const float* bc1  = (const float*)d_in[10];
    const float* Wc2  = (const float*)d_in[11];
    const float* bc2  = (const float*)d_in[12];
    float* out = (float*)d_out;

    char* w = (char*)d_ws;
    int* flag   = (int*)w;          w += 256;
    int* bsum   = (int*)w;          w += 1024;
    int* boff   = (int*)w;          w += 1024;
    unsigned int* sd = (unsigned int*)w; w += (size_t)NE * 4;
    int* seq    = (int*)w;          w += (size_t)NE * 4;
    int* rank   = (int*)w;          w += (size_t)NE * 4;
    float* outsort = (float*)w;     w += (size_t)NE * 4;
    int* cnt    = (int*)w;          w += (size_t)NN * 4;
    int* rowptr = (int*)w;          w += (size_t)(NN + 1) * 4;
    w = (char*)(((size_t)w + 255) & ~(size_t)255);
    int4* rec = (int4*)w;                       w += (size_t)NE * 16;
    unsigned short* w1hi = (unsigned short*)w;  w += 128 * 256 * 2;
    unsigned short* w1lo = (unsigned short*)w;  w += 128 * 256 * 2;
    unsigned short* w2hi = (unsigned short*)w;  w += 128 * 256 * 2;
    unsigned short* w2lo = (unsigned short*)w;  w += 128 * 256 * 2;
    unsigned short* wchi = (unsigned short*)w;  w += 256 * 128 * 2;
    unsigned short* wclo = (unsigned short*)w;  w += 256 * 128 * 2;
    unsigned short* xh   = (unsigned short*)w;  w += (size_t)NN * F * 2;
    unsigned short* aggh = (unsigned short*)w;  w += (size_t)NN * F * 2;
    unsigned short* h1h  = (unsigned short*)w;  w += (size_t)NN * F * 2;
    // aliases: xh dead after conv1 GEMM; aggh consumed per-tile inside k_c2c
    // before the same rows' Gdb outputs are written (barrier between phases;
    // each m-tile owned by exactly one block).
    unsigned short* Gsh = xh;
    unsigned short* Gdh = aggh;

    // flag probe + cnt zeroing in one dispatch (no hipMemsetAsync)
    k_detect<<<1 + NBLK, 256, 0, stream>>>((const unsigned int*)ei, flag, cnt);

    // fused: bf16 casts + weight preps + edge-index normalize/histogram
    k_prep<<<6634 + CVB, 256, 0, stream>>>(x, xh, W1l, W1r, w1hi, w1lo,
                                           W2l, W2r, w2hi, w2lo, Wc1, wchi, wclo,
                                           ei, flag, sd, seq, cnt);

    // CSR build + dst-sorted packed edge records (atomic-free scatter)
    k_bsum<<<NBLK, 256, 0, stream>>>(cnt, bsum);
    k_bscan<<<1, 256, 0, stream>>>(bsum, boff);
    k_scan2<<<NBLK, 256, 0, stream>>>(cnt, boff, rowptr);
    k_perm<<<(NE + 255) / 256, 256, 0, stream>>>(sd, seq, ea, rowptr, rec, rank);

    const int mmBlocks = 1024;
    const int nstripes = (mmBlocks * 4) / 8;  // 512
    int agblocks = (NN + 15) / 16;

    // conv1: agg1 = mean-gather(xh); h1 = relu(agg1@W1l + x@W1r + b1l)
    k_gather<<<agblocks, 256, 0, stream>>>(xh, rowptr, rec, aggh);
    k_mm_conv<<<mmBlocks, 256, 0, stream>>>(aggh, xh, w1hi, w1lo, b1l, h1h, 1, nstripes);

    // conv2 + classifier node-side, fused (streamed weights, 4 waves/SIMD):
    //   agg2 = mean-gather(h1);  h2 = agg2@W2l + h1@W2r + b2l (LDS only);
    //   Gs = h2@Wc1[src-part], Gdb = h2@Wc1[dst-part] + bc1
    k_gather<<<agblocks, 256, 0, stream>>>(h1h, rowptr, rec, aggh);
    k_c2c<<<C2CGRID, 512, 0, stream>>>(aggh, h1h, w2hi, w2lo, b2l,
                                       wchi, wclo, bc1, Gsh, Gdh);

    // edge pass over dst-sorted records (coalesced outsort), then unpermute
    k_edge<<<EBLK, 256, 0, stream>>>(Gsh, Gdh, rec, Wc1 + 256 * F, Wc2, bc2, outsort);
    k_unperm<<<(NE + 255) / 256, 256, 0, stream>>>(outsort, rank, out);
}

// Round 10
// 342.955 us; speedup vs baseline: 1.1141x; 1.1141x over previous
//
#include <hip/hip_runtime.h>

#define NN 50000
#define NE 800000
#define F 128
#define NBLK ((NN + 255) / 256)   // 196 scan blocks
#define NMT (NN / 16)             // 3125 m-tiles, exact
#define NST2 ((NMT + 1) / 2)      // 1563 supertiles (2 m-tiles each)
#define C2CGRID 256               // one block per CU, grid-stride
#define NQ (NE / 4)               // 200000 edge-quads
#define EBLK 4096                 // k_edge grid
#define QPB ((NQ + EBLK - 1) / EBLK)  // 49 quad-slots per block
#define CVB ((NE + 255) / 256)    // 3125 convert blocks (fused into k_prep, FIRST)

typedef __attribute__((ext_vector_type(4))) unsigned short ushort4_t;
typedef __attribute__((ext_vector_type(8))) unsigned short ushort8_t;
typedef __attribute__((ext_vector_type(8))) short bf16x8;
typedef __attribute__((ext_vector_type(4))) float f32x4;

#define MFMA16x16x32 __builtin_amdgcn_mfma_f32_16x16x32_bf16

__device__ __forceinline__ float b2f(unsigned short u) {
    return __uint_as_float((unsigned int)u << 16);
}
__device__ __forceinline__ unsigned short f2b(float f) {
    unsigned int u = __float_as_uint(f);
    return (unsigned short)((u + 0x7fffu + ((u >> 16) & 1u)) >> 16);
}

// ---------------------------------------------------------------------------
// dtype probe (block 0) + cnt[] zeroing (blocks 1..196).
// ---------------------------------------------------------------------------
__global__ void k_detect(const unsigned int* __restrict__ w, int* __restrict__ nz,
                         int* __restrict__ cnt) {
    if (blockIdx.x == 0) {
        __shared__ int s;
        if (threadIdx.x == 0) s = 0;
        __syncthreads();
        if (w[2 * threadIdx.x + 1] != 0u) atomicAdd(&s, 1);
        __syncthreads();
        if (threadIdx.x == 0) *nz = s;
    } else {
        int i = (blockIdx.x - 1) * 256 + threadIdx.x;
        if (i < NN) cnt[i] = 0;
    }
}

// ---------------------------------------------------------------------------
// Fused edge-convert + prep. CONVERT BLOCKS FIRST (0..CVB-1): blocks launch
// roughly in dispatch order, so the latency-bound 800K-atomic histogram
// starts immediately and the streaming casts/weight preps (blocks CVB..)
// fill the machine around it -> merged duration ~ max(parts), not sum
// (round-8 measured sum=56us because convert was last).
//   blocks 0..3124          edge_index normalize -> sd, seq capture, histogram
//   blocks 3125..9374       bf16 cast of x
//   blocks 9375..9502       W1 prep (hi+lo)
//   blocks 9503..9630       W2 prep
//   blocks 9631..9758       Wc1 prep
// ---------------------------------------------------------------------------
__device__ __forceinline__ void prepw_conv_body(int i, const float* __restrict__ WA,
                                                const float* __restrict__ WB,
                                                unsigned short* __restrict__ hi,
                                                unsigned short* __restrict__ lo) {
    int n = i >> 8, k = i & 255;
    float v = (k < 128) ? WA[(size_t)k * F + n] : WB[(size_t)(k - 128) * F + n];
    unsigned short h = f2b(v);
    hi[(size_t)n * 256 + k] = h;
    lo[(size_t)n * 256 + k] = f2b(v - b2f(h));
}

__global__ void k_prep(const float* __restrict__ x, unsigned short* __restrict__ xh,
                       const float* __restrict__ W1l, const float* __restrict__ W1r,
                       unsigned short* __restrict__ w1hi, unsigned short* __restrict__ w1lo,
                       const float* __restrict__ W2l, const float* __restrict__ W2r,
                       unsigned short* __restrict__ w2hi, unsigned short* __restrict__ w2lo,
                       const float* __restrict__ Wc1,
                       unsigned short* __restrict__ wchi, unsigned short* __restrict__ wclo,
                       const void* __restrict__ ei, const int* __restrict__ nz,
                       unsigned int* __restrict__ sd, int* __restrict__ seq,
                       int* __restrict__ cnt) {
    int b = blockIdx.x;
    if (b < CVB) {                        // edge-index normalize + histogram
        int e = b * 256 + threadIdx.x;
        if (e >= NE) return;
        int s, d;
        if (*nz == 0) {
            const long long* p = (const long long*)ei;
            s = (int)p[e];
            d = (int)p[NE + e];
        } else {
            const int* p = (const int*)ei;
            s = p[e];
            d = p[NE + e];
        }
        sd[e] = (unsigned)s | ((unsigned)d << 16);
        seq[e] = atomicAdd(&cnt[d], 1);
    } else if (b < CVB + 6250) {          // cast: NN*F/4 = 1.6M float4 groups
        int i = (b - CVB) * 256 + threadIdx.x;
        float4 v = ((const float4*)x)[i];
        ushort4_t o;
        o.x = f2b(v.x); o.y = f2b(v.y); o.z = f2b(v.z); o.w = f2b(v.w);
        ((ushort4_t*)xh)[i] = o;
    } else if (b < CVB + 6378) {
        prepw_conv_body((b - CVB - 6250) * 256 + threadIdx.x, W1l, W1r, w1hi, w1lo);
    } else if (b < CVB + 6506) {
        prepw_conv_body((b - CVB - 6378) * 256 + threadIdx.x, W2l, W2r, w2hi, w2lo);
    } else {
        int i = (b - CVB - 6506) * 256 + threadIdx.x;
        int n = i >> 7, k = i & 127;
        float v = (n < 128) ? Wc1[(size_t)k * F + n]
                            : Wc1[(size_t)(128 + k) * F + (n - 128)];
        unsigned short h = f2b(v);
        wchi[(size_t)n * 128 + k] = h;
        wclo[(size_t)n * 128 + k] = f2b(v - b2f(h));
    }
}

// ---- exclusive scan of cnt[NN] -> rowptr[NN+1]
__global__ void k_bsum(const int* __restrict__ cnt, int* __restrict__ bsum) {
    __shared__ int s[256];
    int i = blockIdx.x * 256 + threadIdx.x;
    s[threadIdx.x] = (i < NN) ? cnt[i] : 0;
    __syncthreads();
    for (int st = 128; st > 0; st >>= 1) {
        if (threadIdx.x < st) s[threadIdx.x] += s[threadIdx.x + st];
        __syncthreads();
    }
    if (threadIdx.x == 0) bsum[blockIdx.x] = s[0];
}

__global__ void k_bscan(const int* __restrict__ bsum, int* __restrict__ boff) {
    __shared__ int s[256];
    int v = (threadIdx.x < NBLK) ? bsum[threadIdx.x] : 0;
    s[threadIdx.x] = v;
    __syncthreads();
    for (int st = 1; st < 256; st <<= 1) {
        int t = (threadIdx.x >= st) ? s[threadIdx.x - st] : 0;
        __syncthreads();
        s[threadIdx.x] += t;
        __syncthreads();
    }
    if (threadIdx.x < NBLK) boff[threadIdx.x] = s[threadIdx.x] - v;
}

__global__ void k_scan2(const int* __restrict__ cnt, const int* __restrict__ boff,
                        int* __restrict__ rowptr) {
    __shared__ int s[256];
    int i = blockIdx.x * 256 + threadIdx.x;
    int v = (i < NN) ? cnt[i] : 0;
    s[threadIdx.x] = v;
    __syncthreads();
    for (int st = 1; st < 256; st <<= 1) {
        int t = (threadIdx.x >= st) ? s[threadIdx.x - st] : 0;
        __syncthreads();
        s[threadIdx.x] += t;
        __syncthreads();
    }
    int excl = s[threadIdx.x] - v + boff[blockIdx.x];
    if (i < NN) rowptr[i] = excl;
    if (i == NN - 1) rowptr[NN] = excl + v;
}

// counting-sort edges by dst into ONE packed 16B record per edge:
//   rec[pos] = { src | dst<<16, ea0, ea1, ea2 }
// pos = rowptr[dst] + seq[e]  -- NO atomics (seq captured during k_prep).
__global__ void k_perm(const unsigned int* __restrict__ sd,
                       const int* __restrict__ seq,
                       const float* __restrict__ ea,
                       const int* __restrict__ rowptr,
                       int4* __restrict__ rec, int* __restrict__ rank) {
    int e = blockIdx.x * 256 + threadIdx.x;
    if (e >= NE) return;
    unsigned v = sd[e];
    int d = (int)(v >> 16);
    int pos = rowptr[d] + seq[e];
    int4 r;
    r.x = (int)v;
    r.y = __float_as_int(ea[(size_t)e * 3 + 0]);
    r.z = __float_as_int(ea[(size_t)e * 3 + 1]);
    r.w = __float_as_int(ea[(size_t)e * 3 + 2]);
    rec[pos] = r;
    rank[e] = pos;
}

// gather-reduce + mean over bf16 rows -> bf16 out. 16 lanes/node, 8 ch/lane.
__launch_bounds__(256)
__global__ void k_gather(const unsigned short* __restrict__ xin,
                         const int* __restrict__ rowptr,
                         const int4* __restrict__ rec,
                         unsigned short* __restrict__ agg) {
    int n = blockIdx.x * 16 + (threadIdx.x >> 4);
    if (n >= NN) return;
    int c = (threadIdx.x & 15) << 3;
    int beg = rowptr[n], end = rowptr[n + 1];
    float acc[8] = {};
    int j = beg;
    for (; j + 4 <= end; j += 4) {
        int s0 = rec[j].x & 0xffff;
        int s1 = rec[j + 1].x & 0xffff;
        int s2 = rec[j + 2].x & 0xffff;
        int s3 = rec[j + 3].x & 0xffff;
        ushort8_t v0 = *(const ushort8_t*)(xin + (size_t)s0 * F + c);
        ushort8_t v1 = *(const ushort8_t*)(xin + (size_t)s1 * F + c);
        ushort8_t v2 = *(const ushort8_t*)(xin + (size_t)s2 * F + c);
        ushort8_t v3 = *(const ushort8_t*)(xin + (size_t)s3 * F + c);
#pragma unroll
        for (int k = 0; k < 8; ++k)
            acc[k] += (b2f(v0[k]) + b2f(v1[k])) + (b2f(v2[k]) + b2f(v3[k]));
    }
    for (; j < end; ++j) {
        int s = rec[j].x & 0xffff;
        ushort8_t v = *(const ushort8_t*)(xin + (size_t)s * F + c);
#pragma unroll
        for (int k = 0; k < 8; ++k) acc[k] += b2f(v[k]);
    }
    float sc = 1.0f / (float)max(end - beg, 1);
    ushort8_t o;
#pragma unroll
    for (int k = 0; k < 8; ++k) o[k] = f2b(acc[k] * sc);
    *(ushort8_t*)(agg + (size_t)n * F + c) = o;
}

// ---------------------------------------------------------------------------
// Conv1 GEMM, W-in-registers (bf16 data, W exact as hi+lo, dual acc chains).
// ---------------------------------------------------------------------------
__launch_bounds__(256)
__global__ void k_mm_conv(const unsigned short* __restrict__ A1,
                          const unsigned short* __restrict__ A2,
                          const unsigned short* __restrict__ Whi,
                          const unsigned short* __restrict__ Wlo,
                          const float* __restrict__ bias,
                          unsigned short* __restrict__ Ch,
                          int relu, int nstripes) {
    int lane = threadIdx.x & 63;
    int wid = (blockIdx.x * 256 + threadIdx.x) >> 6;
    int ntile = wid & 7;
    int stripe = wid >> 3;
    int lm = lane & 15, quad = lane >> 4;

    const unsigned short* whp = Whi + (size_t)(ntile * 16 + lm) * 256 + quad * 8;
    const unsigned short* wlp = Wlo + (size_t)(ntile * 16 + lm) * 256 + quad * 8;
    bf16x8 wh[8], wl[8];
#pragma unroll
    for (int kc = 0; kc < 8; ++kc) {
        wh[kc] = *(const bf16x8*)(whp + kc * 32);
        wl[kc] = *(const bf16x8*)(wlp + kc * 32);
    }
    int nc = ntile * 16 + quad * 4;
    f32x4 bfrag = *(const f32x4*)(bias + nc);

    for (int mt = stripe; mt < NMT; mt += nstripes) {
        int m = mt * 16 + lm;
        const unsigned short* a1p = A1 + (size_t)m * F + quad * 8;
        const unsigned short* a2p = A2 + (size_t)m * F + quad * 8;
        f32x4 accH = {0.f, 0.f, 0.f, 0.f};
        f32x4 accL = {0.f, 0.f, 0.f, 0.f};
#pragma unroll
        for (int kc = 0; kc < 4; ++kc) {
            bf16x8 d = *(const bf16x8*)(a1p + kc * 32);
            accH = MFMA16x16x32(wh[kc], d, accH, 0, 0, 0);
            accL = MFMA16x16x32(wl[kc], d, accL, 0, 0, 0);
        }
#pragma unroll
        for (int kc = 0; kc < 4; ++kc) {
            bf16x8 d = *(const bf16x8*)(a2p + kc * 32);
            accH = MFMA16x16x32(wh[4 + kc], d, accH, 0, 0, 0);
            accL = MFMA16x16x32(wl[4 + kc], d, accL, 0, 0, 0);
        }
        ushort4_t u;
#pragma unroll
        for (int r = 0; r < 4; ++r) {
            float o = accH[r] + accL[r] + bfrag[r];
            if (relu) o = fmaxf(o, 0.f);
            u[r] = f2b(o);
        }
        *(ushort4_t*)(Ch + (size_t)m * F + nc) = u;
    }
}

// ---------------------------------------------------------------------------
// Fused conv2 + classifier GEMM (round-6 variant, PLATEAUED ~49us — keep):
// grid = 256 (one block per CU), grid-stride over 1563 supertiles of 2
// m-tiles; weights held in registers (48 frags/wave ~192 regs -> 2 waves/
// SIMD). Measured alternatives: LDS-staged A = 53.8, streamed weights = 88
// (L2 miss flood, FETCH 13.5->144MB), unfused pair = ~56. This is the best
// point of the family; do not revisit without a new mechanism.
// ---------------------------------------------------------------------------
__launch_bounds__(512)
__global__ void k_c2c(const unsigned short* __restrict__ A1,   // agg2
                      const unsigned short* __restrict__ A2,   // h1
                      const unsigned short* __restrict__ W2hi,
                      const unsigned short* __restrict__ W2lo,
                      const float* __restrict__ b2l,
                      const unsigned short* __restrict__ Wchi,
                      const unsigned short* __restrict__ Wclo,
                      const float* __restrict__ bc1,
                      unsigned short* __restrict__ Gs,
                      unsigned short* __restrict__ Gdb) {
    __shared__ unsigned short h2s[2][16][136];
    int lane = threadIdx.x & 63;
    int wv = threadIdx.x >> 6;            // 0..7
    int lm = lane & 15, quad = lane >> 4;
    int nc = wv * 16 + quad * 4;

    // conv2 W slice for n-tile wv (held)
    const unsigned short* whp = W2hi + (size_t)(wv * 16 + lm) * 256 + quad * 8;
    const unsigned short* wlp = W2lo + (size_t)(wv * 16 + lm) * 256 + quad * 8;
    bf16x8 wh[8], wl[8];
#pragma unroll
    for (int kc = 0; kc < 8; ++kc) {
        wh[kc] = *(const bf16x8*)(whp + kc * 32);
        wl[kc] = *(const bf16x8*)(wlp + kc * 32);
    }
    f32x4 bfrag2 = *(const f32x4*)(b2l + nc);

    // cls W slices: t0 = wv (Gs), t1 = wv+8 (Gdb) (held)
    const unsigned short* c0hp = Wchi + (size_t)(wv * 16 + lm) * 128 + quad * 8;
    const unsigned short* c0lp = Wclo + (size_t)(wv * 16 + lm) * 128 + quad * 8;
    const unsigned short* c1hp = Wchi + (size_t)((wv + 8) * 16 + lm) * 128 + quad * 8;
    const unsigned short* c1lp = Wclo + (size_t)((wv + 8) * 16 + lm) * 128 + quad * 8;
    bf16x8 ch0[4], cl0[4], ch1[4], cl1[4];
#pragma unroll
    for (int kc = 0; kc < 4; ++kc) {
        ch0[kc] = *(const bf16x8*)(c0hp + kc * 32);
        cl0[kc] = *(const bf16x8*)(c0lp + kc * 32);
        ch1[kc] = *(const bf16x8*)(c1hp + kc * 32);
        cl1[kc] = *(const bf16x8*)(c1lp + kc * 32);
    }
    f32x4 bfragc = *(const f32x4*)(bc1 + nc);

    for (int st = blockIdx.x; st < NST2; st += C2CGRID) {
        int mt0 = st * 2;
        int mt1 = mt0 + 1;
        int mt1c = (mt1 < NMT) ? mt1 : mt0;   // clamp (dup work, benign)
        int m0 = mt0 * 16 + lm;
        int m1 = mt1c * 16 + lm;

        // ---- phase A: issue ALL 16 loads for both tiles up front
        const unsigned short* p0a = A1 + (size_t)m0 * F + quad * 8;
        const unsigned short* p0b = A2 + (size_t)m0 * F + quad * 8;
        const unsigned short* p1a = A1 + (size_t)m1 * F + quad * 8;
        const unsigned short* p1b = A2 + (size_t)m1 * F + quad * 8;
        bf16x8 s0a[4], s0b[4], s1a[4], s1b[4];
#pragma unroll
        for (int kc = 0; kc < 4; ++kc) {
            s0a[kc] = *(const bf16x8*)(p0a + kc * 32);
            s0b[kc] = *(const bf16x8*)(p0b + kc * 32);
            s1a[kc] = *(const bf16x8*)(p1a + kc * 32);
            s1b[kc] = *(const bf16x8*)(p1b + kc * 32);
        }
        f32x4 aH0 = {0.f,0.f,0.f,0.f}, aL0 = {0.f,0.f,0.f,0.f};
        f32x4 aH1 = {0.f,0.f,0.f,0.f}, aL1 = {0.f,0.f,0.f,0.f};
#pragma unroll
        for (int kc = 0; kc < 4; ++kc) {
            aH0 = MFMA16x16x32(wh[kc], s0a[kc], aH0, 0, 0, 0);
            aL0 = MFMA16x16x32(wl[kc], s0a[kc], aL0, 0, 0, 0);
            aH1 = MFMA16x16x32(wh[kc], s1a[kc], aH1, 0, 0, 0);
            aL1 = MFMA16x16x32(wl[kc], s1a[kc], aL1, 0, 0, 0);
        }
#pragma unroll
        for (int kc = 0; kc < 4; ++kc) {
            aH0 = MFMA16x16x32(wh[4 + kc], s0b[kc], aH0, 0, 0, 0);
            aL0 = MFMA16x16x32(wl[4 + kc], s0b[kc], aL0, 0, 0, 0);
            aH1 = MFMA16x16x32(wh[4 + kc], s1b[kc], aH1, 0, 0, 0);
            aL1 = MFMA16x16x32(wl[4 + kc], s1b[kc], aL1, 0, 0, 0);
        }
        ushort4_t u0, u1;
#pragma unroll
        for (int r = 0; r < 4; ++r) {
            u0[r] = f2b(aH0[r] + aL0[r] + bfrag2[r]);
            u1[r] = f2b(aH1[r] + aL1[r] + bfrag2[r]);
        }
        *(ushort4_t*)(&h2s[0][lm][nc]) = u0;
        *(ushort4_t*)(&h2s[1][lm][nc]) = u1;
        __syncthreads();

        // ---- phase B: cls for both tiles from LDS
        const unsigned short* ap0 = &h2s[0][lm][quad * 8];
        const unsigned short* ap1 = &h2s[1][lm][quad * 8];
        f32x4 g0H = {0.f,0.f,0.f,0.f}, g0L = {0.f,0.f,0.f,0.f};
        f32x4 g1H = {0.f,0.f,0.f,0.f}, g1L = {0.f,0.f,0.f,0.f};
        f32x4 g2H = {0.f,0.f,0.f,0.f}, g2L = {0.f,0.f,0.f,0.f};
        f32x4 g3H = {0.f,0.f,0.f,0.f}, g3L = {0.f,0.f,0.f,0.f};
#pragma unroll
        for (int kc = 0; kc < 4; ++kc) {
            bf16x8 d0 = *(const bf16x8*)(ap0 + kc * 32);
            bf16x8 d1 = *(const bf16x8*)(ap1 + kc * 32);
            g0H = MFMA16x16x32(ch0[kc], d0, g0H, 0, 0, 0);
            g0L = MFMA16x16x32(cl0[kc], d0, g0L, 0, 0, 0);
            g1H = MFMA16x16x32(ch1[kc], d0, g1H, 0, 0, 0);
            g1L = MFMA16x16x32(cl1[kc], d0, g1L, 0, 0, 0);
            g2H = MFMA16x16x32(ch0[kc], d1, g2H, 0, 0, 0);
            g2L = MFMA16x16x32(cl0[kc], d1, g2L, 0, 0, 0);
            g3H = MFMA16x16x32(ch1[kc], d1, g3H, 0, 0, 0);
            g3L = MFMA16x16x32(cl1[kc], d1, g3L, 0, 0, 0);
        }
        ushort4_t o0, o1, o2, o3;
#pragma unroll
        for (int r = 0; r < 4; ++r) {
            o0[r] = f2b(g0H[r] + g0L[r]);
            o1[r] = f2b(g1H[r] + g1L[r] + bfragc[r]);
            o2[r] = f2b(g2H[r] + g2L[r]);
            o3[r] = f2b(g3H[r] + g3L[r] + bfragc[r]);
        }
        *(ushort4_t*)(Gs  + (size_t)m0 * F + nc) = o0;
        *(ushort4_t*)(Gdb + (size_t)m0 * F + nc) = o1;
        if (mt1 < NMT) {
            *(ushort4_t*)(Gs  + (size_t)m1 * F + nc) = o2;
            *(ushort4_t*)(Gdb + (size_t)m1 * F + nc) = o3;
        }
        __syncthreads();
    }
}

// ---------------------------------------------------------------------------
// edge classifier over dst-sorted packed records, 4 edges per 16-lane group:
// 8 G-row loads in flight per group, bc1 pre-folded into Gdb. XCD-contiguous
// chunking keeps each XCD's dst window L2-resident. Coalesced float4 store.
// ---------------------------------------------------------------------------
__launch_bounds__(256)
__global__ void k_edge(const unsigned short* __restrict__ Gs,
                       const unsigned short* __restrict__ Gdb,
                       const int4* __restrict__ rec,
                       const float* __restrict__ Wc1e,
                       const float* __restrict__ Wc2,
                       const float* __restrict__ bc2,
                       float* __restrict__ outsort) {
    int lane = threadIdx.x & 15;
    int c = lane << 3;
    float w0[8], w1[8], w2[8], wc[8];
#pragma unroll
    for (int k = 0; k < 8; ++k) {
        w0[k] = Wc1e[0 * F + c + k];
        w1[k] = Wc1e[1 * F + c + k];
        w2[k] = Wc1e[2 * F + c + k];
        wc[k] = Wc2[c + k];
    }
    float bout = bc2[0];

    int subgrp = threadIdx.x >> 4;                       // 16 groups/block
    int wblk = ((blockIdx.x & 7) << 9) | (blockIdx.x >> 3);  // XCD-contiguous
    int base = wblk * QPB;
    int lim = base + QPB;
    if (lim > NQ) lim = NQ;

    for (int q = base + subgrp; q < lim; q += 16) {
        int pos = q * 4;
        int4 r0 = rec[pos];
        int4 r1 = rec[pos + 1];
        int4 r2 = rec[pos + 2];
        int4 r3 = rec[pos + 3];
        unsigned u0 = (unsigned)r0.x, u1 = (unsigned)r1.x;
        unsigned u2 = (unsigned)r2.x, u3 = (unsigned)r3.x;
        ushort8_t gs0 = *(const ushort8_t*)(Gs  + (size_t)(u0 & 0xffffu) * F + c);
        ushort8_t gd0 = *(const ushort8_t*)(Gdb + (size_t)(u0 >> 16) * F + c);
        ushort8_t gs1 = *(const ushort8_t*)(Gs  + (size_t)(u1 & 0xffffu) * F + c);
        ushort8_t gd1 = *(const ushort8_t*)(Gdb + (size_t)(u1 >> 16) * F + c);
        ushort8_t gs2 = *(const ushort8_t*)(Gs  + (size_t)(u2 & 0xffffu) * F + c);
        ushort8_t gd2 = *(const ushort8_t*)(Gdb + (size_t)(u2 >> 16) * F + c);
        ushort8_t gs3 = *(const ushort8_t*)(Gs  + (size_t)(u3 & 0xffffu) * F + c);
        ushort8_t gd3 = *(const ushort8_t*)(Gdb + (size_t)(u3 >> 16) * F + c);

        float ex0 = __int_as_float(r0.y), ey0 = __int_as_float(r0.z), ez0 = __int_as_float(r0.w);
        float ex1 = __int_as_float(r1.y), ey1 = __int_as_float(r1.z), ez1 = __int_as_float(r1.w);
        float ex2 = __int_as_float(r2.y), ey2 = __int_as_float(r2.z), ez2 = __int_as_float(r2.w);
        float ex3 = __int_as_float(r3.y), ey3 = __int_as_float(r3.z), ez3 = __int_as_float(r3.w);

        float p0 = 0.f, p1 = 0.f, p2 = 0.f, p3 = 0.f;
#pragma unroll
        for (int k = 0; k < 8; ++k) {
            float h0 = b2f(gs0[k]) + b2f(gd0[k]) + ex0 * w0[k] + ey0 * w1[k] + ez0 * w2[k];
            float h1 = b2f(gs1[k]) + b2f(gd1[k]) + ex1 * w0[k] + ey1 * w1[k] + ez1 * w2[k];
            float h2 = b2f(gs2[k]) + b2f(gd2[k]) + ex2 * w0[k] + ey2 * w1[k] + ez2 * w2[k];
            float h3 = b2f(gs3[k]) + b2f(gd3[k]) + ex3 * w0[k] + ey3 * w1[k] + ez3 * w2[k];
            p0 += fmaxf(h0, 0.f) * wc[k];
            p1 += fmaxf(h1, 0.f) * wc[k];
            p2 += fmaxf(h2, 0.f) * wc[k];
            p3 += fmaxf(h3, 0.f) * wc[k];
        }
#pragma unroll
        for (int off = 8; off > 0; off >>= 1) {
            p0 += __shfl_down(p0, off, 16);
            p1 += __shfl_down(p1, off, 16);
            p2 += __shfl_down(p2, off, 16);
            p3 += __shfl_down(p3, off, 16);
        }
        if (lane == 0) {
            float4 o;
            o.x = p0 + bout; o.y = p1 + bout; o.z = p2 + bout; o.w = p3 + bout;
            *(float4*)(outsort + pos) = o;
        }
    }
}

// out[e] = outsort[rank[e]] — coalesced read of rank + write of out;
// random reads hit the 3.2MB L2-hot outsort.
__global__ void k_unperm(const float* __restrict__ outsort,
                         const int* __restrict__ rank,
                         float* __restrict__ out) {
    int e = blockIdx.x * 256 + threadIdx.x;
    if (e >= NE) return;
    out[e] = outsort[rank[e]];
}

// ---------------------------------------------------------------------------
extern "C" void kernel_launch(void* const* d_in, const int* in_sizes, int n_in,
                              void* d_out, int out_size, void* d_ws, size_t ws_size,
                              hipStream_t stream) {
    const float* x    = (const float*)d_in[0];
    const void*  ei   = d_in[1];
    const float* ea   = (const float*)d_in[2];
    const float* W1l  = (const float*)d_in[3];
    const float* b1l  = (const float*)d_in[4];
    const float* W1r  = (const float*)d_in[5];
    const float* W2l  = (const float*)d_in[6];
    const float* b2l  = (const float*)d_in[7];
    const float* W2r  = (const float*)d_in[8];
    const float* Wc1  = (const float*)d_in[9];
    const float* bc1  = (const float*)d_in[10];
    const float* Wc2  = (const float*)d_in[11];
    const float* bc2  = (const float*)d_in[12];
    float* out = (float*)d_out;

    char* w = (char*)d_ws;
    int* flag   = (int*)w;          w += 256;
    int* bsum   = (int*)w;          w += 1024;
    int* boff   = (int*)w;          w += 1024;
    unsigned int* sd = (unsigned int*)w; w += (size_t)NE * 4;
    int* seq    = (int*)w;          w += (size_t)NE * 4;
    int* rank   = (int*)w;          w += (size_t)NE * 4;
    float* outsort = (float*)w;     w += (size_t)NE * 4;
    int* cnt    = (int*)w;          w += (size_t)NN * 4;
    int* rowptr = (int*)w;          w += (size_t)(NN + 1) * 4;
    w = (char*)(((size_t)w + 255) & ~(size_t)255);
    int4* rec = (int4*)w;                       w += (size_t)NE * 16;
    unsigned short* w1hi = (unsigned short*)w;  w += 128 * 256 * 2;
    unsigned short* w1lo = (unsigned short*)w;  w += 128 * 256 * 2;
    unsigned short* w2hi = (unsigned short*)w;  w += 128 * 256 * 2;
    unsigned short* w2lo = (unsigned short*)w;  w += 128 * 256 * 2;
    unsigned short* wchi = (unsigned short*)w;  w += 256 * 128 * 2;
    unsigned short* wclo = (unsigned short*)w;  w += 256 * 128 * 2;
    unsigned short* xh   = (unsigned short*)w;  w += (size_t)NN * F * 2;
    unsigned short* aggh = (unsigned short*)w;  w += (size_t)NN * F * 2;
    unsigned short* h1h  = (unsigned short*)w;  w += (size_t)NN * F * 2;
    // aliases: xh dead after conv1 GEMM; aggh consumed per-supertile inside
    // k_c2c before the same rows' Gdb outputs are written (barrier between
    // phases; each supertile's rows owned by exactly one block).
    unsigned short* Gsh = xh;
    unsigned short* Gdh = aggh;

    // flag probe + cnt zeroing in one dispatch (no hipMemsetAsync)
    k_detect<<<1 + NBLK, 256, 0, stream>>>((const unsigned int*)ei, flag, cnt);

    // fused: edge-index normalize/histogram FIRST, then casts + weight preps
    k_prep<<<CVB + 6634, 256, 0, stream>>>(x, xh, W1l, W1r, w1hi, w1lo,
                                           W2l, W2r, w2hi, w2lo, Wc1, wchi, wclo,
                                           ei, flag, sd, seq, cnt);

    // CSR build + dst-sorted packed edge records (atomic-free scatter)
    k_bsum<<<NBLK, 256, 0, stream>>>(cnt, bsum);
    k_bscan<<<1, 256, 0, stream>>>(bsum, boff);
    k_scan2<<<NBLK, 256, 0, stream>>>(cnt, boff, rowptr);
    k_perm<<<(NE + 255) / 256, 256, 0, stream>>>(sd, seq, ea, rowptr, rec, rank);

    const int mmBlocks = 1024;
    const int nstripes = (mmBlocks * 4) / 8;  // 512
    int agblocks = (NN + 15) / 16;

    // conv1: agg1 = mean-gather(xh); h1 = relu(agg1@W1l + x@W1r + b1l)
    k_gather<<<agblocks, 256, 0, stream>>>(xh, rowptr, rec, aggh);
    k_mm_conv<<<mmBlocks, 256, 0, stream>>>(aggh, xh, w1hi, w1lo, b1l, h1h, 1, nstripes);

    // conv2 + classifier node-side, fused (grid=256, supertile=2):
    //   agg2 = mean-gather(h1);  h2 = agg2@W2l + h1@W2r + b2l (LDS only);
    //   Gs = h2@Wc1[src-part], Gdb = h2@Wc1[dst-part] + bc1
    k_gather<<<agblocks, 256, 0, stream>>>(h1h, rowptr, rec, aggh);
    k_c2c<<<C2CGRID, 512, 0, stream>>>(aggh, h1h, w2hi, w2lo, b2l,
                                       wchi, wclo, bc1, Gsh, Gdh);

    // edge pass over dst-sorted records (coalesced outsort), then unpermute
    k_edge<<<EBLK, 256, 0, stream>>>(Gsh, Gdh, rec, Wc1 + 256 * F, Wc2, bc2, outsort);
    k_unperm<<<(NE + 255) / 256, 256, 0, stream>>>(outsort, rank, out);
}

// Round 12
// 313.882 us; speedup vs baseline: 1.2173x; 1.0926x over previous
//
#include <hip/hip_runtime.h>

#define NN 50000
#define NE 800000
#define F 128
#define NBLK ((NN + 255) / 256)   // 196 scan blocks
#define NMT (NN / 16)             // 3125 m-tiles, exact
#define MMGRID ((NMT + 15) / 16)  // 196 blocks x 16 waves = 1 tile/wave
#define NQ (NE / 4)               // 200000 edge-quads
#define EBLK 4096                 // k_edge grid
#define QPB ((NQ + EBLK - 1) / EBLK)  // 49 quad-slots per block
#define CVB ((NE + 255) / 256)    // 3125 convert blocks (fused into k_prep, FIRST)

typedef __attribute__((ext_vector_type(4))) unsigned short ushort4_t;
typedef __attribute__((ext_vector_type(8))) unsigned short ushort8_t;
typedef __attribute__((ext_vector_type(8))) short bf16x8;
typedef __attribute__((ext_vector_type(4))) float f32x4;

#define MFMA16x16x32 __builtin_amdgcn_mfma_f32_16x16x32_bf16

__device__ __forceinline__ float b2f(unsigned short u) {
    return __uint_as_float((unsigned int)u << 16);
}
__device__ __forceinline__ unsigned short f2b(float f) {
    unsigned int u = __float_as_uint(f);
    return (unsigned short)((u + 0x7fffu + ((u >> 16) & 1u)) >> 16);
}

// ---------------------------------------------------------------------------
// dtype probe (block 0) + cnt[] zeroing (blocks 1..196).
// ---------------------------------------------------------------------------
__global__ void k_detect(const unsigned int* __restrict__ w, int* __restrict__ nz,
                         int* __restrict__ cnt) {
    if (blockIdx.x == 0) {
        __shared__ int s;
        if (threadIdx.x == 0) s = 0;
        __syncthreads();
        if (w[2 * threadIdx.x + 1] != 0u) atomicAdd(&s, 1);
        __syncthreads();
        if (threadIdx.x == 0) *nz = s;
    } else {
        int i = (blockIdx.x - 1) * 256 + threadIdx.x;
        if (i < NN) cnt[i] = 0;
    }
}

// ---------------------------------------------------------------------------
// Fused edge-convert + prep. CONVERT BLOCKS FIRST (latency-bound atomics
// start immediately; streaming casts/preps fill the machine around them).
// ---------------------------------------------------------------------------
__device__ __forceinline__ void prepw_conv_body(int i, const float* __restrict__ WA,
                                                const float* __restrict__ WB,
                                                unsigned short* __restrict__ hi,
                                                unsigned short* __restrict__ lo) {
    int n = i >> 8, k = i & 255;
    float v = (k < 128) ? WA[(size_t)k * F + n] : WB[(size_t)(k - 128) * F + n];
    unsigned short h = f2b(v);
    hi[(size_t)n * 256 + k] = h;
    lo[(size_t)n * 256 + k] = f2b(v - b2f(h));
}

__global__ void k_prep(const float* __restrict__ x, unsigned short* __restrict__ xh,
                       const float* __restrict__ W1l, const float* __restrict__ W1r,
                       unsigned short* __restrict__ w1hi, unsigned short* __restrict__ w1lo,
                       const float* __restrict__ W2l, const float* __restrict__ W2r,
                       unsigned short* __restrict__ w2hi, unsigned short* __restrict__ w2lo,
                       const float* __restrict__ Wc1,
                       unsigned short* __restrict__ wchi, unsigned short* __restrict__ wclo,
                       const void* __restrict__ ei, const int* __restrict__ nz,
                       unsigned int* __restrict__ sd, int* __restrict__ seq,
                       int* __restrict__ cnt) {
    int b = blockIdx.x;
    if (b < CVB) {                        // edge-index normalize + histogram
        int e = b * 256 + threadIdx.x;
        if (e >= NE) return;
        int s, d;
        if (*nz == 0) {
            const long long* p = (const long long*)ei;
            s = (int)p[e];
            d = (int)p[NE + e];
        } else {
            const int* p = (const int*)ei;
            s = p[e];
            d = p[NE + e];
        }
        sd[e] = (unsigned)s | ((unsigned)d << 16);
        seq[e] = atomicAdd(&cnt[d], 1);
    } else if (b < CVB + 6250) {          // cast: NN*F/4 = 1.6M float4 groups
        int i = (b - CVB) * 256 + threadIdx.x;
        float4 v = ((const float4*)x)[i];
        ushort4_t o;
        o.x = f2b(v.x); o.y = f2b(v.y); o.z = f2b(v.z); o.w = f2b(v.w);
        ((ushort4_t*)xh)[i] = o;
    } else if (b < CVB + 6378) {
        prepw_conv_body((b - CVB - 6250) * 256 + threadIdx.x, W1l, W1r, w1hi, w1lo);
    } else if (b < CVB + 6506) {
        prepw_conv_body((b - CVB - 6378) * 256 + threadIdx.x, W2l, W2r, w2hi, w2lo);
    } else {
        int i = (b - CVB - 6506) * 256 + threadIdx.x;
        int n = i >> 7, k = i & 127;
        float v = (n < 128) ? Wc1[(size_t)k * F + n]
                            : Wc1[(size_t)(128 + k) * F + (n - 128)];
        unsigned short h = f2b(v);
        wchi[(size_t)n * 128 + k] = h;
        wclo[(size_t)n * 128 + k] = f2b(v - b2f(h));
    }
}

// ---- exclusive scan of cnt[NN] -> rowptr[NN+1]
__global__ void k_bsum(const int* __restrict__ cnt, int* __restrict__ bsum) {
    __shared__ int s[256];
    int i = blockIdx.x * 256 + threadIdx.x;
    s[threadIdx.x] = (i < NN) ? cnt[i] : 0;
    __syncthreads();
    for (int st = 128; st > 0; st >>= 1) {
        if (threadIdx.x < st) s[threadIdx.x] += s[threadIdx.x + st];
        __syncthreads();
    }
    if (threadIdx.x == 0) bsum[blockIdx.x] = s[0];
}

__global__ void k_bscan(const int* __restrict__ bsum, int* __restrict__ boff) {
    __shared__ int s[256];
    int v = (threadIdx.x < NBLK) ? bsum[threadIdx.x] : 0;
    s[threadIdx.x] = v;
    __syncthreads();
    for (int st = 1; st < 256; st <<= 1) {
        int t = (threadIdx.x >= st) ? s[threadIdx.x - st] : 0;
        __syncthreads();
        s[threadIdx.x] += t;
        __syncthreads();
    }
    if (threadIdx.x < NBLK) boff[threadIdx.x] = s[threadIdx.x] - v;
}

__global__ void k_scan2(const int* __restrict__ cnt, const int* __restrict__ boff,
                        int* __restrict__ rowptr) {
    __shared__ int s[256];
    int i = blockIdx.x * 256 + threadIdx.x;
    int v = (i < NN) ? cnt[i] : 0;
    s[threadIdx.x] = v;
    __syncthreads();
    for (int st = 1; st < 256; st <<= 1) {
        int t = (threadIdx.x >= st) ? s[threadIdx.x - st] : 0;
        __syncthreads();
        s[threadIdx.x] += t;
        __syncthreads();
    }
    int excl = s[threadIdx.x] - v + boff[blockIdx.x];
    if (i < NN) rowptr[i] = excl;
    if (i == NN - 1) rowptr[NN] = excl + v;
}

// counting-sort edges by dst into ONE packed 16B record per edge.
__global__ void k_perm(const unsigned int* __restrict__ sd,
                       const int* __restrict__ seq,
                       const float* __restrict__ ea,
                       const int* __restrict__ rowptr,
                       int4* __restrict__ rec, int* __restrict__ rank) {
    int e = blockIdx.x * 256 + threadIdx.x;
    if (e >= NE) return;
    unsigned v = sd[e];
    int d = (int)(v >> 16);
    int pos = rowptr[d] + seq[e];
    int4 r;
    r.x = (int)v;
    r.y = __float_as_int(ea[(size_t)e * 3 + 0]);
    r.z = __float_as_int(ea[(size_t)e * 3 + 1]);
    r.w = __float_as_int(ea[(size_t)e * 3 + 2]);
    rec[pos] = r;
    rank[e] = pos;
}

// gather-reduce + mean over bf16 rows -> bf16 out. 16 lanes/node, 8 ch/lane.
__launch_bounds__(256)
__global__ void k_gather(const unsigned short* __restrict__ xin,
                         const int* __restrict__ rowptr,
                         const int4* __restrict__ rec,
                         unsigned short* __restrict__ agg) {
    int n = blockIdx.x * 16 + (threadIdx.x >> 4);
    if (n >= NN) return;
    int c = (threadIdx.x & 15) << 3;
    int beg = rowptr[n], end = rowptr[n + 1];
    float acc[8] = {};
    int j = beg;
    for (; j + 4 <= end; j += 4) {
        int s0 = rec[j].x & 0xffff;
        int s1 = rec[j + 1].x & 0xffff;
        int s2 = rec[j + 2].x & 0xffff;
        int s3 = rec[j + 3].x & 0xffff;
        ushort8_t v0 = *(const ushort8_t*)(xin + (size_t)s0 * F + c);
        ushort8_t v1 = *(const ushort8_t*)(xin + (size_t)s1 * F + c);
        ushort8_t v2 = *(const ushort8_t*)(xin + (size_t)s2 * F + c);
        ushort8_t v3 = *(const ushort8_t*)(xin + (size_t)s3 * F + c);
#pragma unroll
        for (int k = 0; k < 8; ++k)
            acc[k] += (b2f(v0[k]) + b2f(v1[k])) + (b2f(v2[k]) + b2f(v3[k]));
    }
    for (; j < end; ++j) {
        int s = rec[j].x & 0xffff;
        ushort8_t v = *(const ushort8_t*)(xin + (size_t)s * F + c);
#pragma unroll
        for (int k = 0; k < 8; ++k) acc[k] += b2f(v[k]);
    }
    float sc = 1.0f / (float)max(end - beg, 1);
    ushort8_t o;
#pragma unroll
    for (int k = 0; k < 8; ++k) o[k] = f2b(acc[k] * sc);
    *(ushort8_t*)(agg + (size_t)n * F + c) = o;
}

// ---------------------------------------------------------------------------
// Conv GEMM v6: WEIGHTS IN LDS, loaded once per block. Mechanism: r4-r10
// showed register-held weights (~128+ regs/wave) cap occupancy at 2 waves/
// SIMD -> latency-bound 49us at 9% MfmaUtil; streamed weights flood L2
// (88us). Here weights live in 64KB LDS (one L2 preload per block), regs
// drop -> 4 waves/SIMD. K=256 split in 2 halves (LDS can't hold both);
// acc persists across halves, so ONE output tile per wave
// (grid 196 x 1024 threads = 3136 waves >= 3125 tiles).
// XOR row-swizzle keeps the 16-row-strided W reads at ds_read_b128 baseline.
// hi+lo both accumulate into the same f32 acc (same sum, fewer regs).
// ---------------------------------------------------------------------------
__launch_bounds__(1024, 4)
__global__ void k_mm_lds(const unsigned short* __restrict__ A1,
                         const unsigned short* __restrict__ A2,
                         const unsigned short* __restrict__ Whi,
                         const unsigned short* __restrict__ Wlo,
                         const float* __restrict__ bias,
                         unsigned short* __restrict__ Ch, int relu) {
    __shared__ unsigned short wl[2][128][128];   // [hi/lo][n][k-half] swizzled
    int tid = threadIdx.x;
    int lane = tid & 63;
    int wv = tid >> 6;                 // 0..15
    int lm = lane & 15, quad = lane >> 4;
    int mt = blockIdx.x * 16 + wv;     // one m-tile per wave
    int m = mt * 16 + lm;
    const int swz = (lm & 7) << 4;

    f32x4 acc[8] = {};
#pragma unroll
    for (int h = 0; h < 2; ++h) {
        // cooperative preload of K-half h (hi+lo), XOR-swizzled rows
#pragma unroll
        for (int it = 0; it < 2; ++it) {
            int flat = (it * 1024 + tid) * 8;        // 16384 ushorts = 128x128
            int n = flat >> 7, kk = flat & 127;
            ushort8_t vh = *(const ushort8_t*)(Whi + (size_t)n * 256 + h * 128 + kk);
            ushort8_t vl = *(const ushort8_t*)(Wlo + (size_t)n * 256 + h * 128 + kk);
            int byo = (kk * 2) ^ ((n & 7) << 4);
            *(ushort8_t*)((char*)&wl[0][n][0] + byo) = vh;
            *(ushort8_t*)((char*)&wl[1][n][0] + byo) = vl;
        }
        __syncthreads();
        if (mt < NMT) {
            const unsigned short* ap = (h == 0 ? A1 : A2) + (size_t)m * F + quad * 8;
            bf16x8 a[4];
#pragma unroll
            for (int kc = 0; kc < 4; ++kc) a[kc] = *(const bf16x8*)(ap + kc * 32);
#pragma unroll
            for (int kc = 0; kc < 4; ++kc) {
#pragma unroll
                for (int nt = 0; nt < 8; ++nt) {
                    int row = nt * 16 + lm;
                    int cb = (kc * 64 + quad * 16) ^ swz;
                    bf16x8 wh_ = *(const bf16x8*)((const char*)&wl[0][row][0] + cb);
                    bf16x8 wl_ = *(const bf16x8*)((const char*)&wl[1][row][0] + cb);
                    acc[nt] = MFMA16x16x32(wh_, a[kc], acc[nt], 0, 0, 0);
                    acc[nt] = MFMA16x16x32(wl_, a[kc], acc[nt], 0, 0, 0);
                }
            }
        }
        __syncthreads();   // protect LDS before half-2 overwrite
    }
    if (mt < NMT) {
#pragma unroll
        for (int nt = 0; nt < 8; ++nt) {
            int nc = nt * 16 + quad * 4;
            f32x4 b4 = *(const f32x4*)(bias + nc);
            ushort4_t u;
#pragma unroll
            for (int r = 0; r < 4; ++r) {
                float o = acc[nt][r] + b4[r];
                if (relu) o = fmaxf(o, 0.f);
                u[r] = f2b(o);
            }
            *(ushort4_t*)(Ch + (size_t)m * F + nc) = u;
        }
    }
}

// ---------------------------------------------------------------------------
// Classifier GEMM v6 (same LDS-weight mechanism): Gs = h2@Wc[0:128],
// Gdb = h2@Wc[128:256] + bc1. K=128 split in 2 halves of 64.
// ---------------------------------------------------------------------------
__launch_bounds__(1024, 4)
__global__ void k_cls_lds(const unsigned short* __restrict__ A,
                          const unsigned short* __restrict__ Whi,
                          const unsigned short* __restrict__ Wlo,
                          const float* __restrict__ bc1,
                          unsigned short* __restrict__ Gs,
                          unsigned short* __restrict__ Gdb) {
    __shared__ unsigned short wl[2][256][64];    // [hi/lo][n][k-half] swizzled
    int tid = threadIdx.x;
    int lane = tid & 63;
    int wv = tid >> 6;
    int lm = lane & 15, quad = lane >> 4;
    int mt = blockIdx.x * 16 + wv;
    int m = mt * 16 + lm;
    const int swz = (lm & 7) << 4;

    f32x4 acc[16] = {};
#pragma unroll
    for (int h = 0; h < 2; ++h) {
#pragma unroll
        for (int it = 0; it < 2; ++it) {
            int flat = (it * 1024 + tid) * 8;        // 16384 ushorts = 256x64
            int n = flat >> 6, kk = flat & 63;
            ushort8_t vh = *(const ushort8_t*)(Whi + (size_t)n * 128 + h * 64 + kk);
            ushort8_t vl = *(const ushort8_t*)(Wlo + (size_t)n * 128 + h * 64 + kk);
            int byo = (kk * 2) ^ ((n & 7) << 4);
            *(ushort8_t*)((char*)&wl[0][n][0] + byo) = vh;
            *(ushort8_t*)((char*)&wl[1][n][0] + byo) = vl;
        }
        __syncthreads();
        if (mt < NMT) {
            const unsigned short* ap = A + (size_t)m * F + h * 64 + quad * 8;
            bf16x8 a[2];
#pragma unroll
            for (int kc = 0; kc < 2; ++kc) a[kc] = *(const bf16x8*)(ap + kc * 32);
#pragma unroll
            for (int kc = 0; kc < 2; ++kc) {
#pragma unroll
                for (int nt = 0; nt < 16; ++nt) {
                    int row = nt * 16 + lm;
                    int cb = (kc * 64 + quad * 16) ^ swz;
                    bf16x8 wh_ = *(const bf16x8*)((const char*)&wl[0][row][0] + cb);
                    bf16x8 wl_ = *(const bf16x8*)((const char*)&wl[1][row][0] + cb);
                    acc[nt] = MFMA16x16x32(wh_, a[kc], acc[nt], 0, 0, 0);
                    acc[nt] = MFMA16x16x32(wl_, a[kc], acc[nt], 0, 0, 0);
                }
            }
        }
        __syncthreads();
    }
    if (mt < NMT) {
#pragma unroll
        for (int nt = 0; nt < 8; ++nt) {
            int nc = nt * 16 + quad * 4;
            ushort4_t u;
#pragma unroll
            for (int r = 0; r < 4; ++r) u[r] = f2b(acc[nt][r]);
            *(ushort4_t*)(Gs + (size_t)m * F + nc) = u;
        }
#pragma unroll
        for (int nt = 8; nt < 16; ++nt) {
            int nc = (nt - 8) * 16 + quad * 4;
            f32x4 b4 = *(const f32x4*)(bc1 + nc);
            ushort4_t u;
#pragma unroll
            for (int r = 0; r < 4; ++r) u[r] = f2b(acc[nt][r] + b4[r]);
            *(ushort4_t*)(Gdb + (size_t)m * F + nc) = u;
        }
    }
}

// ---------------------------------------------------------------------------
// edge classifier over dst-sorted packed records, 4 edges per 16-lane group.
// ---------------------------------------------------------------------------
__launch_bounds__(256)
__global__ void k_edge(const unsigned short* __restrict__ Gs,
                       const unsigned short* __restrict__ Gdb,
                       const int4* __restrict__ rec,
                       const float* __restrict__ Wc1e,
                       const float* __restrict__ Wc2,
                       const float* __restrict__ bc2,
                       float* __restrict__ outsort) {
    int lane = threadIdx.x & 15;
    int c = lane << 3;
    float w0[8], w1[8], w2[8], wc[8];
#pragma unroll
    for (int k = 0; k < 8; ++k) {
        w0[k] = Wc1e[0 * F + c + k];
        w1[k] = Wc1e[1 * F + c + k];
        w2[k] = Wc1e[2 * F + c + k];
        wc[k] = Wc2[c + k];
    }
    float bout = bc2[0];

    int subgrp = threadIdx.x >> 4;                       // 16 groups/block
    int wblk = ((blockIdx.x & 7) << 9) | (blockIdx.x >> 3);  // XCD-contiguous
    int base = wblk * QPB;
    int lim = base + QPB;
    if (lim > NQ) lim = NQ;

    for (int q = base + subgrp; q < lim; q += 16) {
        int pos = q * 4;
        int4 r0 = rec[pos];
        int4 r1 = rec[pos + 1];
        int4 r2 = rec[pos + 2];
        int4 r3 = rec[pos + 3];
        unsigned u0 = (unsigned)r0.x, u1 = (unsigned)r1.x;
        unsigned u2 = (unsigned)r2.x, u3 = (unsigned)r3.x;
        ushort8_t gs0 = *(const ushort8_t*)(Gs  + (size_t)(u0 & 0xffffu) * F + c);
        ushort8_t gd0 = *(const ushort8_t*)(Gdb + (size_t)(u0 >> 16) * F + c);
        ushort8_t gs1 = *(const ushort8_t*)(Gs  + (size_t)(u1 & 0xffffu) * F + c);
        ushort8_t gd1 = *(const ushort8_t*)(Gdb + (size_t)(u1 >> 16) * F + c);
        ushort8_t gs2 = *(const ushort8_t*)(Gs  + (size_t)(u2 & 0xffffu) * F + c);
        ushort8_t gd2 = *(const ushort8_t*)(Gdb + (size_t)(u2 >> 16) * F + c);
        ushort8_t gs3 = *(const ushort8_t*)(Gs  + (size_t)(u3 & 0xffffu) * F + c);
        ushort8_t gd3 = *(const ushort8_t*)(Gdb + (size_t)(u3 >> 16) * F + c);

        float ex0 = __int_as_float(r0.y), ey0 = __int_as_float(r0.z), ez0 = __int_as_float(r0.w);
        float ex1 = __int_as_float(r1.y), ey1 = __int_as_float(r1.z), ez1 = __int_as_float(r1.w);
        float ex2 = __int_as_float(r2.y), ey2 = __int_as_float(r2.z), ez2 = __int_as_float(r2.w);
        float ex3 = __int_as_float(r3.y), ey3 = __int_as_float(r3.z), ez3 = __int_as_float(r3.w);

        float p0 = 0.f, p1 = 0.f, p2 = 0.f, p3 = 0.f;
#pragma unroll
        for (int k = 0; k < 8; ++k) {
            float h0 = b2f(gs0[k]) + b2f(gd0[k]) + ex0 * w0[k] + ey0 * w1[k] + ez0 * w2[k];
            float h1 = b2f(gs1[k]) + b2f(gd1[k]) + ex1 * w0[k] + ey1 * w1[k] + ez1 * w2[k];
            float h2 = b2f(gs2[k]) + b2f(gd2[k]) + ex2 * w0[k] + ey2 * w1[k] + ez2 * w2[k];
            float h3 = b2f(gs3[k]) + b2f(gd3[k]) + ex3 * w0[k] + ey3 * w1[k] + ez3 * w2[k];
            p0 += fmaxf(h0, 0.f) * wc[k];
            p1 += fmaxf(h1, 0.f) * wc[k];
            p2 += fmaxf(h2, 0.f) * wc[k];
            p3 += fmaxf(h3, 0.f) * wc[k];
        }
#pragma unroll
        for (int off = 8; off > 0; off >>= 1) {
            p0 += __shfl_down(p0, off, 16);
            p1 += __shfl_down(p1, off, 16);
            p2 += __shfl_down(p2, off, 16);
            p3 += __shfl_down(p3, off, 16);
        }
        if (lane == 0) {
            float4 o;
            o.x = p0 + bout; o.y = p1 + bout; o.z = p2 + bout; o.w = p3 + bout;
            *(float4*)(outsort + pos) = o;
        }
    }
}

// out[e] = outsort[rank[e]] — coalesced read of rank + write of out.
__global__ void k_unperm(const float* __restrict__ outsort,
                         const int* __restrict__ rank,
                         float* __restrict__ out) {
    int e = blockIdx.x * 256 + threadIdx.x;
    if (e >= NE) return;
    out[e] = outsort[rank[e]];
}

// ---------------------------------------------------------------------------
extern "C" void kernel_launch(void* const* d_in, const int* in_sizes, int n_in,
                              void* d_out, int out_size, void* d_ws, size_t ws_size,
                              hipStream_t stream) {
    const float* x    = (const float*)d_in[0];
    const void*  ei   = d_in[1];
    const float* ea   = (const float*)d_in[2];
    const float* W1l  = (const float*)d_in[3];
    const float* b1l  = (const float*)d_in[4];
    const float* W1r  = (const float*)d_in[5];
    const float* W2l  = (const float*)d_in[6];
    const float* b2l  = (const float*)d_in[7];
    const float* W2r  = (const float*)d_in[8];
    const float* Wc1  = (const float*)d_in[9];
    const float* bc1  = (const float*)d_in[10];
    const float* Wc2  = (const float*)d_in[11];
    const float* bc2  = (const float*)d_in[12];
    float* out = (float*)d_out;

    char* w = (char*)d_ws;
    int* flag   = (int*)w;          w += 256;
    int* bsum   = (int*)w;          w += 1024;
    int* boff   = (int*)w;          w += 1024;
    unsigned int* sd = (unsigned int*)w; w += (size_t)NE * 4;
    int* seq    = (int*)w;          w += (size_t)NE * 4;
    int* rank   = (int*)w;          w += (size_t)NE * 4;
    float* outsort = (float*)w;     w += (size_t)NE * 4;
    int* cnt    = (int*)w;          w += (size_t)NN * 4;
    int* rowptr = (int*)w;          w += (size_t)(NN + 1) * 4;
    w = (char*)(((size_t)w + 255) & ~(size_t)255);
    int4* rec = (int4*)w;                       w += (size_t)NE * 16;
    unsigned short* w1hi = (unsigned short*)w;  w += 128 * 256 * 2;
    unsigned short* w1lo = (unsigned short*)w;  w += 128 * 256 * 2;
    unsigned short* w2hi = (unsigned short*)w;  w += 128 * 256 * 2;
    unsigned short* w2lo = (unsigned short*)w;  w += 128 * 256 * 2;
    unsigned short* wchi = (unsigned short*)w;  w += 256 * 128 * 2;
    unsigned short* wclo = (unsigned short*)w;  w += 256 * 128 * 2;
    unsigned short* xh   = (unsigned short*)w;  w += (size_t)NN * F * 2;
    unsigned short* aggh = (unsigned short*)w;  w += (size_t)NN * F * 2;
    unsigned short* h1h  = (unsigned short*)w;  w += (size_t)NN * F * 2;
    unsigned short* h2h  = (unsigned short*)w;  w += (size_t)NN * F * 2;
    // aliases: xh dead after conv1 GEMM (reads it as A2); aggh dead after
    // conv2 GEMM (reads it as A1). Gs/Gdb written by cls afterward.
    unsigned short* Gsh = xh;
    unsigned short* Gdh = aggh;

    // flag probe + cnt zeroing in one dispatch (no hipMemsetAsync)
    k_detect<<<1 + NBLK, 256, 0, stream>>>((const unsigned int*)ei, flag, cnt);

    // fused: edge-index normalize/histogram FIRST, then casts + weight preps
    k_prep<<<CVB + 6634, 256, 0, stream>>>(x, xh, W1l, W1r, w1hi, w1lo,
                                           W2l, W2r, w2hi, w2lo, Wc1, wchi, wclo,
                                           ei, flag, sd, seq, cnt);

    // CSR build + dst-sorted packed edge records (atomic-free scatter)
    k_bsum<<<NBLK, 256, 0, stream>>>(cnt, bsum);
    k_bscan<<<1, 256, 0, stream>>>(bsum, boff);
    k_scan2<<<NBLK, 256, 0, stream>>>(cnt, boff, rowptr);
    k_perm<<<(NE + 255) / 256, 256, 0, stream>>>(sd, seq, ea, rowptr, rec, rank);

    int agblocks = (NN + 15) / 16;

    // conv1: agg1 = mean-gather(xh); h1 = relu(agg1@W1l + x@W1r + b1l)
    k_gather<<<agblocks, 256, 0, stream>>>(xh, rowptr, rec, aggh);
    k_mm_lds<<<MMGRID, 1024, 0, stream>>>(aggh, xh, w1hi, w1lo, b1l, h1h, 1);

    // conv2: agg2 = mean-gather(h1); h2 = agg2@W2l + h1@W2r + b2l
    k_gather<<<agblocks, 256, 0, stream>>>(h1h, rowptr, rec, aggh);
    k_mm_lds<<<MMGRID, 1024, 0, stream>>>(aggh, h1h, w2hi, w2lo, b2l, h2h, 0);

    // classifier node-side: Gs = h2@Wc1[src], Gdb = h2@Wc1[dst] + bc1
    k_cls_lds<<<MMGRID, 1024, 0, stream>>>(h2h, wchi, wclo, bc1, Gsh, Gdh);

    // edge pass over dst-sorted records (coalesced outsort), then unpermute
    k_edge<<<EBLK, 256, 0, stream>>>(Gsh, Gdh, rec, Wc1 + 256 * F, Wc2, bc2, outsort);
    k_unperm<<<(NE + 255) / 256, 256, 0, stream>>>(outsort, rank, out);
}